// Round 1
// 282.470 us; speedup vs baseline: 1.0317x; 1.0317x over previous
//
#include <hip/hip_runtime.h>
#include <hip/hip_fp16.h>

#define N_NODES 50000
#define N_EDGES 1600000
#define D_IN    128
#define D_HID   50
#define D_OUT   10
#define K_CHEB  5

// bucket sort params: bucket = row >> 8 (196 buckets of 256 rows), block-private strips
#define P1_BLOCKS 256
#define EPB       (N_EDGES / P1_BLOCKS)   // 6250 edges per scatter block
#define NBUCK2    256                     // padded bucket count (196 used)
#define NB_USED2  196
#define BCAP2     96                      // strip capacity; mean 32, sd ~5.7 -> +11 sd

#define WH_ELEMS  (K_CHEB * 64 * D_IN)    // 40960 halfs (W^T, n padded to 64)
#define WH_BLOCKS ((WH_ELEMS + 255) / 256)        // 160
#define XH_BLOCKS (N_NODES * D_IN / 8 / 256)      // 3125 (exact)

#define VROW      64                      // padded hidden row (halfs) = 128 B
#define VSTRIDE   ((size_t)(N_NODES + 1) * VROW)  // +1 zeroed pad row

#define NGROUP    (N_NODES / 16)          // 3125 node groups (exact)
#define VG_SPAN   512                     // waves per term
#define VG_WAVES  (K_CHEB * VG_SPAN)      // 2560 waves
#define VG_BLOCKS (VG_WAVES / 4)          // 640 blocks x 4 waves

typedef _Float16 half8_t __attribute__((ext_vector_type(8)));
typedef float    f32x4_t __attribute__((ext_vector_type(4)));

// Clenshaw in hidden space. R17: vgemm stores UNSCALED u_t = x @ W_t; the dinv
// scaling moves into the props (row-side dinv[r] on addv/subv, col-side dinv[c]
// on the first prop's gather only). This breaks vgemm's dependency on pass2 so
// vgemm fuses into pass1's dispatch (both were underutilized: pass1 had 1
// block/CU latency-bound on LDS atomics; vgemm was request-bound). x is
// converted to fp16 ONCE in prep (identical rounding to the old per-use
// convert), halving vgemm's 5x re-read of x. b3/b2 get dedicated buffers so all
// pad rows clear in prep (drops 2 memset launches). Dispatches 10 -> 8.

// ---------------- prep: xh convert + Wh build + pad clears ----------------
__global__ __launch_bounds__(256) void prep_kernel(const float* __restrict__ x,
                                                   const float* __restrict__ W,
                                                   __half* __restrict__ xh,
                                                   __half* __restrict__ Wh,
                                                   __half* __restrict__ u,
                                                   __half* __restrict__ b1,
                                                   __half* __restrict__ b3,
                                                   __half* __restrict__ b2,
                                                   float* __restrict__ dinv) {
    int tid = threadIdx.x;
    int blk = blockIdx.x;
    if (blk < XH_BLOCKS) {                // x (fp32) -> xh (fp16), 8 elems/thread
        size_t base = ((size_t)blk * 256 + tid) * 8;
        float4 a = *(const float4*)(x + base);
        float4 b = *(const float4*)(x + base + 4);
        half8_t h;
        h[0] = (_Float16)a.x; h[1] = (_Float16)a.y;
        h[2] = (_Float16)a.z; h[3] = (_Float16)a.w;
        h[4] = (_Float16)b.x; h[5] = (_Float16)b.y;
        h[6] = (_Float16)b.z; h[7] = (_Float16)b.w;
        *(half8_t*)(xh + base) = h;
    } else if (blk < XH_BLOCKS + WH_BLOCKS) {  // Wh = fp16 W^T padded: [t][n<64][i<128]
        int idx = (blk - XH_BLOCKS) * 256 + tid;
        if (idx < WH_ELEMS) {
            int i = idx & 127;
            int n = (idx >> 7) & 63;
            int t = idx >> 13;
            float vv = (n < D_HID) ? W[t * D_IN * D_HID + i * D_HID + n] : 0.f;
            Wh[idx] = __float2half(vv);
        }
    } else {                              // zero all gather-target pad rows
        if (tid < VROW) {
            __half z = __float2half(0.f);
            u[4 * VSTRIDE + (size_t)N_NODES * VROW + tid] = z;   // u4 pad
            b1[(size_t)N_NODES * VROW + tid] = z;
            b3[(size_t)N_NODES * VROW + tid] = z;
            b2[(size_t)N_NODES * VROW + tid] = z;
        }
        if (tid == 64) dinv[N_NODES] = 0.f;   // pad entry read by masked lanes
    }
}

// -------- fused: vgemm (blocks 0..639) + pass1 edge scatter (640..895) --------
// vgemm: wave w holds term t=w/512's 16 A-frags in registers (loaded once from
// Wh, L2-hot) and grid-strides node groups. Per group: 4 half8 x-loads
// (prefetched during previous group's MFMA) + 16 MFMA + 4 stores of UNSCALED u.
// D[m=j][n=node]: lane holds node=lane&15, j = jt*16 + quad*4 + reg.
__global__ __launch_bounds__(256) void fused_kernel(const int* __restrict__ row,
                                                    const int* __restrict__ col,
                                                    unsigned int* __restrict__ store,
                                                    int* __restrict__ bcnt,
                                                    const __half* __restrict__ xh,
                                                    const __half* __restrict__ Wh,
                                                    __half* __restrict__ u) {
    __shared__ int cnt[NBUCK2];
    int tid = threadIdx.x;
    int blk = blockIdx.x;
    if (blk < VG_BLOCKS) {
        int lane = tid & 63;
        int wv = __builtin_amdgcn_readfirstlane(tid >> 6);
        int w = blk * 4 + wv;             // 0..2559; 512%4==0 -> t uniform per block
        int t = w / VG_SPAN;              // 0..4
        int idx = w - t * VG_SPAN;        // 0..511
        int m = lane & 15;                // node within group (B n-index)
        int quad = lane >> 4;             // k-quad

        const __half* Wt = Wh + t * (64 * D_IN);
        half8_t afr[4][4];                // persistent A-frags (64 VGPRs)
        #pragma unroll
        for (int ks = 0; ks < 4; ++ks) {
            int ko = ks * 32 + quad * 8;
            #pragma unroll
            for (int jt = 0; jt < 4; ++jt)
                afr[ks][jt] = *(const half8_t*)(Wt + (jt * 16 + m) * D_IN + ko);
        }

        __half* ut = u + t * VSTRIDE;

        half8_t pf[4];
        int g = idx;
        {
            const __half* xr = xh + (size_t)(g * 16 + m) * D_IN;
            #pragma unroll
            for (int ks = 0; ks < 4; ++ks)
                pf[ks] = *(const half8_t*)(xr + ks * 32 + quad * 8);
        }

        for (; g < NGROUP; g += VG_SPAN) {
            int node = g * 16 + m;
            half8_t bfr[4];
            #pragma unroll
            for (int ks = 0; ks < 4; ++ks) bfr[ks] = pf[ks];
            int gn = g + VG_SPAN;
            if (gn < NGROUP) {            // prefetch next group's x while MFMAs run
                const __half* xr = xh + (size_t)(gn * 16 + m) * D_IN;
                #pragma unroll
                for (int ks = 0; ks < 4; ++ks)
                    pf[ks] = *(const half8_t*)(xr + ks * 32 + quad * 8);
            }
            f32x4_t acc[4];
            #pragma unroll
            for (int jt = 0; jt < 4; ++jt) acc[jt] = (f32x4_t)0.f;
            #pragma unroll
            for (int ks = 0; ks < 4; ++ks)
                #pragma unroll
                for (int jt = 0; jt < 4; ++jt)
                    acc[jt] = __builtin_amdgcn_mfma_f32_16x16x32_f16(afr[ks][jt], bfr[ks], acc[jt], 0, 0, 0);
            __half* dst = ut + (size_t)node * VROW + quad * 4;
            #pragma unroll
            for (int jt = 0; jt < 4; ++jt) {
                __half2 h0 = __float22half2_rn(make_float2(acc[jt][0], acc[jt][1]));
                __half2 h1 = __float22half2_rn(make_float2(acc[jt][2], acc[jt][3]));
                uint2 uu;
                uu.x = *(unsigned int*)&h0;
                uu.y = *(unsigned int*)&h1;
                *(uint2*)(dst + jt * 16) = uu;
            }
        }
        return;
    }
    // ---- pass1 edge scatter ----
    int blk2 = blk - VG_BLOCKS;           // 0..255
    cnt[tid] = 0;
    __syncthreads();
    int base = blk2 * EPB;
    size_t sb = (size_t)blk2 * (NBUCK2 * BCAP2);
    for (int i = tid; i < EPB; i += 256) {
        int r = row[base + i];
        int c = col[base + i];
        int b = r >> 8;
        int pos = atomicAdd(&cnt[b], 1);
        if (pos >= BCAP2) pos = BCAP2 - 1;   // memory-safety clamp; P(hit) ~ 0
        store[sb + b * BCAP2 + pos] = ((unsigned int)(r & 255) << 16) | (unsigned int)c;
    }
    __syncthreads();
    bcnt[blk2 * NBUCK2 + tid] = cnt[tid];
}

// ---------------- pass 2: per-bucket CSR build (one block per bucket) ----
__global__ __launch_bounds__(512) void pass2_kernel(const unsigned int* __restrict__ store,
                                                    const int* __restrict__ bcnt,
                                                    int* __restrict__ row_start,
                                                    float* __restrict__ dinv,
                                                    float* __restrict__ dinv2,
                                                    float* __restrict__ sdeg,
                                                    int* __restrict__ ewc) {
    __shared__ int hist[256];
    __shared__ int off[256];
    __shared__ int fill[256];
    __shared__ int sb_part[512];
    __shared__ int pscan[256];
    __shared__ int s_bbase;
    int tid = threadIdx.x;
    int b = blockIdx.x;

    // phase 0: bucket totals + exclusive prefix (redundant per block)
    {
        int bt = tid & 255, seg = tid >> 8;       // 2 segs x 128 strips
        int sum = 0;
        for (int s = seg * 128; s < seg * 128 + 128; ++s) sum += bcnt[s * NBUCK2 + bt];
        sb_part[tid] = sum;
    }
    __syncthreads();
    if (tid < 256) pscan[tid] = sb_part[tid] + sb_part[256 + tid];
    __syncthreads();
    for (int o = 1; o < 256; o <<= 1) {
        int vv = (tid < 256 && tid >= o) ? pscan[tid - o] : 0;
        __syncthreads();
        if (tid < 256) pscan[tid] += vv;
        __syncthreads();
    }
    if (tid == 0) {
        s_bbase = (b == 0) ? 0 : pscan[b - 1];
        if (b == 0) row_start[N_NODES] = pscan[255];
    }
    if (tid < 256) hist[tid] = 0;
    __syncthreads();
    int bbase_b = s_bbase;

    int strip = tid >> 1;        // 0..255
    int sub   = tid & 1;
    int sn = bcnt[strip * NBUCK2 + b];
    size_t sb = (size_t)strip * (NBUCK2 * BCAP2) + b * BCAP2;
    // phase A: degree histogram — 2 threads sweep each strip
    for (int i = sub; i < sn; i += 2)
        atomicAdd(&hist[store[sb + i] >> 16], 1);
    __syncthreads();
    int d = (tid < 256) ? hist[tid] : 0;
    if (tid < 256) off[tid] = d;
    __syncthreads();
    for (int o = 1; o < 256; o <<= 1) {
        int vv = (tid < 256 && tid >= o) ? off[tid - o] : 0;
        __syncthreads();
        if (tid < 256) off[tid] += vv;
        __syncthreads();
    }
    if (tid < 256) {
        int excl = off[tid] - d + bbase_b;
        hist[tid] = excl;        // reuse as per-row global base
        fill[tid] = 0;
        int r = (b << 8) + tid;
        if (r < N_NODES) {
            row_start[r] = excl;
            float fd = (float)d;
            dinv[r]  = d ? rsqrtf(fd)  : 0.f;
            dinv2[r] = d ? (1.f / fd)  : 0.f;
            sdeg[r]  = d ? sqrtf(fd)   : 0.f;
        }
    }
    __syncthreads();
    // phase C: scatter cols into final CSR (writes confined to this bucket's region)
    for (int i = sub; i < sn; i += 2) {
        unsigned int vv = store[sb + i];
        int rl = vv >> 16;
        int c = vv & 0xffff;
        int p = atomicAdd(&fill[rl], 1);
        ewc[hist[rl] + p] = c;
    }
}

// ---------------- Clenshaw SpMM step in hidden space ----------------
// dst[r] = dinv[r]*addv[r] + (-alphaM*dinv2[r]) * sum_{c in N(r)} sc(c)*src[c]
//          - DO_SUB * (SCALE_SUB ? dinv[r] : 1) * subv[r]
// sc(c) = SCALE_SRC ? dinv[c] : 1. addv is always u-space (scaled by dinv[r]).
// 1 wave/row; 8 lanes x 16 B cover the 128 B row; 8 edges per gather inst.
template<int SCALE_SRC, int DO_SUB, int SCALE_SUB>
__global__ __launch_bounds__(512) void prop_kernel(const int* __restrict__ row_start,
                                                   const int* __restrict__ ewc,
                                                   const float* __restrict__ dinv2,
                                                   const float* __restrict__ dinv,
                                                   const __half* __restrict__ src,
                                                   const __half* __restrict__ addv,
                                                   const __half* __restrict__ subv,
                                                   float alphaM,
                                                   __half* __restrict__ dst) {
    int tid = threadIdx.x;
    int lane = tid & 63;
    int wv = __builtin_amdgcn_readfirstlane(tid >> 6);  // 0..7
    int r = blockIdx.x * 8 + wv;                        // 6250*8 == 50000
    int e0 = row_start[r], e1 = row_start[r + 1];
    float fac = -alphaM * dinv2[r];
    int l = lane & 7;            // uint4 unit within row (8 x 16 B = 128 B)
    int g = lane >> 3;           // edge slot 0..7
    const uint4* src16 = (const uint4*)src;   // row stride 8 uint4
    float ac[8];
    #pragma unroll
    for (int j = 0; j < 8; ++j) ac[j] = 0.f;
    for (int e = e0; e < e1; e += 32) {
        #pragma unroll
        for (int i = 0; i < 4; ++i) {
            int base = e + 8 * i;
            int cl = ewc[base + g];              // per-lane load, 1 line / instr
            if (base + g >= e1) cl = N_NODES;    // zeroed pad row (dinv[N]=0 too)
            uint4 uu = src16[(size_t)cl * 8 + l];
            float2 f0 = __half22float2(*(__half2*)&uu.x);
            float2 f1 = __half22float2(*(__half2*)&uu.y);
            float2 f2 = __half22float2(*(__half2*)&uu.z);
            float2 f3 = __half22float2(*(__half2*)&uu.w);
            if (SCALE_SRC) {
                float dc = dinv[cl];             // broadcast within 8-lane group
                ac[0] = fmaf(dc, f0.x, ac[0]); ac[1] = fmaf(dc, f0.y, ac[1]);
                ac[2] = fmaf(dc, f1.x, ac[2]); ac[3] = fmaf(dc, f1.y, ac[3]);
                ac[4] = fmaf(dc, f2.x, ac[4]); ac[5] = fmaf(dc, f2.y, ac[5]);
                ac[6] = fmaf(dc, f3.x, ac[6]); ac[7] = fmaf(dc, f3.y, ac[7]);
            } else {
                ac[0] += f0.x; ac[1] += f0.y; ac[2] += f1.x; ac[3] += f1.y;
                ac[4] += f2.x; ac[5] += f2.y; ac[6] += f3.x; ac[7] += f3.y;
            }
        }
    }
    // reduce across the 8 edge slots (lane bits 3,4,5)
    #pragma unroll
    for (int k = 8; k <= 32; k <<= 1) {
        #pragma unroll
        for (int j = 0; j < 8; ++j) ac[j] += __shfl_xor(ac[j], k);
    }
    if (g == 0) {
        float sa = dinv[r];              // addv always u-space
        size_t o = (size_t)r * 8 + l;    // uint4 index
        uint4 av = ((const uint4*)addv)[o];
        float2 av0 = __half22float2(*(__half2*)&av.x);
        float2 av1 = __half22float2(*(__half2*)&av.y);
        float2 av2 = __half22float2(*(__half2*)&av.z);
        float2 av3 = __half22float2(*(__half2*)&av.w);
        float r0 = fmaf(sa, av0.x, fac * ac[0]);
        float r1 = fmaf(sa, av0.y, fac * ac[1]);
        float r2 = fmaf(sa, av1.x, fac * ac[2]);
        float r3 = fmaf(sa, av1.y, fac * ac[3]);
        float r4 = fmaf(sa, av2.x, fac * ac[4]);
        float r5 = fmaf(sa, av2.y, fac * ac[5]);
        float r6 = fmaf(sa, av3.x, fac * ac[6]);
        float r7 = fmaf(sa, av3.y, fac * ac[7]);
        if (DO_SUB) {
            float ss = SCALE_SUB ? dinv[r] : 1.f;
            uint4 sv = ((const uint4*)subv)[o];
            float2 sv0 = __half22float2(*(__half2*)&sv.x);
            float2 sv1 = __half22float2(*(__half2*)&sv.y);
            float2 sv2 = __half22float2(*(__half2*)&sv.z);
            float2 sv3 = __half22float2(*(__half2*)&sv.w);
            r0 = fmaf(-ss, sv0.x, r0); r1 = fmaf(-ss, sv0.y, r1);
            r2 = fmaf(-ss, sv1.x, r2); r3 = fmaf(-ss, sv1.y, r3);
            r4 = fmaf(-ss, sv2.x, r4); r5 = fmaf(-ss, sv2.y, r5);
            r6 = fmaf(-ss, sv3.x, r6); r7 = fmaf(-ss, sv3.y, r7);
        }
        __half2 h0 = __float22half2_rn(make_float2(r0, r1));
        __half2 h1 = __float22half2_rn(make_float2(r2, r3));
        __half2 h2 = __float22half2_rn(make_float2(r4, r5));
        __half2 h3 = __float22half2_rn(make_float2(r6, r7));
        uint4 uu;
        uu.x = *(unsigned int*)&h0;
        uu.y = *(unsigned int*)&h1;
        uu.z = *(unsigned int*)&h2;
        uu.w = *(unsigned int*)&h3;
        ((uint4*)dst)[o] = uu;
    }
}

// ---------------- epilogue: relu(sdeg*S + bias) -> FC -> log_softmax ----------------
__global__ __launch_bounds__(256) void final_kernel(const __half* __restrict__ S,
                                                    const float* __restrict__ sdeg,
                                                    const float* __restrict__ cheb_b,
                                                    const float* __restrict__ fc_w,
                                                    const float* __restrict__ fc_b,
                                                    float* __restrict__ out) {
    int r = blockIdx.x * blockDim.x + threadIdx.x;
    if (r >= N_NODES) return;
    float sc = sdeg[r];
    const __half2* s2 = (const __half2*)(S + (size_t)r * VROW);
    float h[D_HID];
    #pragma unroll
    for (int i = 0; i < D_HID / 2; ++i) {
        float2 f = __half22float2(s2[i]);
        float v0 = sc * f.x + cheb_b[2 * i];
        float v1 = sc * f.y + cheb_b[2 * i + 1];
        h[2 * i]     = v0 > 0.f ? v0 : 0.f;
        h[2 * i + 1] = v1 > 0.f ? v1 : 0.f;
    }
    float lg[D_OUT];
    #pragma unroll
    for (int o = 0; o < D_OUT; ++o) lg[o] = fc_b[o];
    #pragma unroll 2
    for (int i = 0; i < D_HID; ++i) {
        float hv = h[i];
        #pragma unroll
        for (int o = 0; o < D_OUT; ++o) lg[o] += hv * fc_w[i * D_OUT + o];
    }
    float mx = lg[0];
    #pragma unroll
    for (int o = 1; o < D_OUT; ++o) mx = fmaxf(mx, lg[o]);
    float s = 0.f;
    #pragma unroll
    for (int o = 0; o < D_OUT; ++o) s += __expf(lg[o] - mx);
    float ls = __logf(s);
    size_t oo = (size_t)r * D_OUT;
    #pragma unroll
    for (int o = 0; o < D_OUT; ++o) out[oo + o] = lg[o] - mx - ls;
}

extern "C" void kernel_launch(void* const* d_in, const int* in_sizes, int n_in,
                              void* d_out, int out_size, void* d_ws, size_t ws_size,
                              hipStream_t stream) {
    const float* x      = (const float*)d_in[0];
    const int*   edge   = (const int*)d_in[1];
    const float* cheb_w = (const float*)d_in[2];
    const float* cheb_b = (const float*)d_in[3];
    const float* fc_w   = (const float*)d_in[4];
    const float* fc_b   = (const float*)d_in[5];
    float* out = (float*)d_out;

    const int* erow = edge;
    const int* ecol = edge + N_EDGES;

    uintptr_t p = ((uintptr_t)d_ws + 255) & ~(uintptr_t)255;
    auto alloc = [&](size_t bytes) {
        uintptr_t q = p;
        p = (p + bytes + 255) & ~(uintptr_t)255;
        return (void*)q;
    };
    unsigned int* store = (unsigned int*)alloc((size_t)P1_BLOCKS * NBUCK2 * BCAP2 * 4);  // 25.2 MB
    int*    bcnt      = (int*)alloc((size_t)P1_BLOCKS * NBUCK2 * 4);
    int*    row_start = (int*)alloc((size_t)(N_NODES + 1) * 4);
    float*  dinv      = (float*)alloc((size_t)(N_NODES + 1) * 4);   // +1 pad (=0)
    float*  dinv2     = (float*)alloc((size_t)N_NODES * 4);
    float*  sdeg      = (float*)alloc((size_t)N_NODES * 4);
    int*    ewc       = (int*)alloc((size_t)(N_EDGES + 32) * 4);    // +32 pad
    __half* Wh        = (__half*)alloc((size_t)WH_ELEMS * 2);       // 80 KB
    __half* xh        = (__half*)alloc((size_t)N_NODES * D_IN * 2); // 12.8 MB
    __half* Sbuf      = (__half*)alloc(VSTRIDE * 2);                // 6.4 MB
    __half* u         = (__half*)alloc(5 * VSTRIDE * 2);            // u0..u4, 32 MB
    __half* b1        = (__half*)alloc(VSTRIDE * 2);
    __half* b3        = (__half*)alloc(VSTRIDE * 2);                // dedicated (no
    __half* b2        = (__half*)alloc(VSTRIDE * 2);                //  store aliasing)
    __half* S  = Sbuf;

    // prep: xh fp16 convert + Wh build + pad-row clears (u4,b1,b3,b2) + dinv pad
    prep_kernel<<<XH_BLOCKS + WH_BLOCKS + 1, 256, 0, stream>>>(
        x, cheb_w, xh, Wh, u, b1, b3, b2, dinv);

    // fused: u_t = x @ W_t (unscaled, persistent-weight MFMA) + pass1 bucket scatter
    fused_kernel<<<VG_BLOCKS + P1_BLOCKS, 256, 0, stream>>>(
        erow, ecol, store, bcnt, xh, Wh, u);

    pass2_kernel<<<NB_USED2, 512, 0, stream>>>(store, bcnt, row_start,
                                               dinv, dinv2, sdeg, ewc);

    __half* u0 = u;
    __half* u1 = u + 1 * VSTRIDE;
    __half* u2 = u + 2 * VSTRIDE;
    __half* u3 = u + 3 * VSTRIDE;
    __half* u4 = u + 4 * VSTRIDE;
    const int PB = N_NODES / 8;   // 6250 blocks x 8 waves
    // b3 = dinv.*u3 + 2M(dinv.*u4)
    prop_kernel<1, 0, 0><<<PB, 512, 0, stream>>>(row_start, ewc, dinv2, dinv,
                                                 u4, u3, u3, 2.f, b3);
    // b2 = dinv.*u2 + 2M b3 - dinv.*u4
    prop_kernel<0, 1, 1><<<PB, 512, 0, stream>>>(row_start, ewc, dinv2, dinv,
                                                 b3, u2, u4, 2.f, b2);
    // b1 = dinv.*u1 + 2M b2 - b3
    prop_kernel<0, 1, 0><<<PB, 512, 0, stream>>>(row_start, ewc, dinv2, dinv,
                                                 b2, u1, b3, 2.f, b1);
    // S = dinv.*u0 + M b1 - b2
    prop_kernel<0, 1, 0><<<PB, 512, 0, stream>>>(row_start, ewc, dinv2, dinv,
                                                 b1, u0, b2, 1.f, S);

    // out = log_softmax(relu(sdeg*S + bias) @ fc_w + fc_b)
    final_kernel<<<(N_NODES + 255) / 256, 256, 0, stream>>>(S, sdeg, cheb_b,
                                                            fc_w, fc_b, out);
}